// Round 1
// baseline (357.831 us; speedup 1.0000x reference)
//
#include <hip/hip_runtime.h>

#define LP 40  // padded LDS row length in bf16 elements (80 B: 16B-aligned, 2-way-conflict only)

typedef __attribute__((ext_vector_type(8))) short short8;
typedef __attribute__((ext_vector_type(4))) short short4t;
typedef __attribute__((ext_vector_type(4))) float f32x4;

__device__ __forceinline__ short f2bf(float f) {
  unsigned u = __builtin_bit_cast(unsigned, f);
  u += 0x7FFFu + ((u >> 16) & 1u);   // round-to-nearest-even
  return (short)(u >> 16);
}

__device__ __forceinline__ float lrelu(float v) { return v >= 0.f ? v : 0.2f * v; }

// ---------------- Kernel 0: wT bf16 [512][512]  (wt[n][c] = w[c][n]) ----------------
__global__ __launch_bounds__(256) void k_wt(const float* __restrict__ w,
                                            short* __restrict__ wt) {
  __shared__ float t[64][65];
  int c0 = (blockIdx.x & 7) * 64;
  int n0 = (blockIdx.x >> 3) * 64;
  int r  = threadIdx.x >> 4;          // 0..15
  int q4 = (threadIdx.x & 15) * 4;    // 0..60
  for (int i = 0; i < 4; i++) {
    int c = r + i * 16;
    f32x4 v = *(const f32x4*)(w + (size_t)(c0 + c) * 512 + (n0 + q4));
    t[c][q4 + 0] = v[0]; t[c][q4 + 1] = v[1]; t[c][q4 + 2] = v[2]; t[c][q4 + 3] = v[3];
  }
  __syncthreads();
  for (int i = 0; i < 4; i++) {
    int n = r + i * 16;
    short4t o;
    for (int j = 0; j < 4; j++) o[j] = f2bf(t[q4 + j][n]);
    *(short4t*)(wt + (size_t)(n0 + n) * 512 + (c0 + q4)) = o;
  }
}

// ------------- Kernel 1: supportT bf16 [512][8192] = (inputs @ w + b)^T -------------
// Block: 512 ch x 64 rows. 8 waves in 4(n) x 2(m). MFMA 16x16x32 bf16.
__global__ __launch_bounds__(512, 2) void k_support(const float* __restrict__ inp,
                                                    const short* __restrict__ wt,
                                                    const float* __restrict__ bias,
                                                    short* __restrict__ sup) {
  __shared__ __align__(16) short As[512 * LP];  // wT tile [512 n][32 q]
  __shared__ __align__(16) short Bs[64 * LP];   // inputs tile [64 m][32 q]
  const int tid = threadIdx.x;
  const int m0 = blockIdx.x * 64;
  const int wave = tid >> 6, lane = tid & 63;
  const int wn = wave >> 1, wm = wave & 1;
  const int lr = lane & 15, lk = lane >> 4;
  const int bm = tid >> 3, bk = (tid & 7) * 4;
  f32x4 acc[8][2] = {};
  short8 ar[4]; f32x4 br;
  auto loadA = [&](int s) {
    const short* p = wt + (size_t)tid * 512 + s * 32;
    ar[0] = *(const short8*)(p);      ar[1] = *(const short8*)(p + 8);
    ar[2] = *(const short8*)(p + 16); ar[3] = *(const short8*)(p + 24);
  };
  auto loadB = [&](int s) {
    br = *(const f32x4*)(inp + (size_t)(m0 + bm) * 512 + s * 32 + bk);
  };
  loadA(0); loadB(0);
  for (int s = 0; s < 16; s++) {
    short* ad = As + tid * LP;
    *(short8*)(ad) = ar[0]; *(short8*)(ad + 8) = ar[1];
    *(short8*)(ad + 16) = ar[2]; *(short8*)(ad + 24) = ar[3];
    short4t bo;
    for (int j = 0; j < 4; j++) bo[j] = f2bf(br[j]);
    *(short4t*)(Bs + bm * LP + bk) = bo;
    __syncthreads();
    if (s + 1 < 16) { loadA(s + 1); loadB(s + 1); }   // reg prefetch spans compute
    short8 af[8], bfr[2];
    for (int nf = 0; nf < 8; nf++)
      af[nf] = *(const short8*)(As + (wn * 128 + nf * 16 + lr) * LP + lk * 8);
    for (int mf = 0; mf < 2; mf++)
      bfr[mf] = *(const short8*)(Bs + (wm * 32 + mf * 16 + lr) * LP + lk * 8);
    for (int nf = 0; nf < 8; nf++)
      for (int mf = 0; mf < 2; mf++)
        acc[nf][mf] = __builtin_amdgcn_mfma_f32_16x16x32_bf16(af[nf], bfr[mf], acc[nf][mf], 0, 0, 0);
    __syncthreads();
  }
  for (int nf = 0; nf < 8; nf++) {
    int nb = wn * 128 + nf * 16 + lk * 4;
    for (int mf = 0; mf < 2; mf++) {
      int m = m0 + wm * 32 + mf * 16 + lr;
      for (int j = 0; j < 4; j++) {
        int n = nb + j;
        sup[(size_t)n * 8192 + m] = f2bf(acc[nf][mf][j] + bias[n]);
      }
    }
  }
}

// ---- Kernel 2: out[m][n] (+partials) = (sum_k att[k]*adj_k) @ support, fused ----
// Grid (128 m-blocks, ksplit). Block: 64 m x 512 n, 8 waves 4(n) x 2(m).
__global__ __launch_bounds__(512, 2) void k_main(const float* __restrict__ adj,
                                                 const float* __restrict__ att,
                                                 const short* __restrict__ sup,
                                                 float* __restrict__ part,
                                                 float* __restrict__ outp,
                                                 int ksplit) {
  __shared__ __align__(16) short As[512 * LP];  // supportT tile [512 n][32 k]
  __shared__ __align__(16) short Bs[64 * LP];   // combined adj tile [64 m][32 k]
  const int tid = threadIdx.x;
  const int m0 = blockIdx.x * 64;
  const int kc = blockIdx.y;
  const int kchunk = 8192 / ksplit;
  const int nsteps = kchunk / 32;
  const int kbase = kc * kchunk;
  const float t0 = att[0], t1 = att[1], t2 = att[2], t3 = att[3];
  const int wave = tid >> 6, lane = tid & 63;
  const int wn = wave >> 1, wm = wave & 1;
  const int lr = lane & 15, lk = lane >> 4;
  const int bm = tid >> 3, bk = (tid & 7) * 4;
  f32x4 acc[8][2] = {};
  const float* adjp = adj + (size_t)(m0 + bm) * 8192 + kbase + bk;
  short8 ar[4]; f32x4 br[4];
  auto loadA = [&](int s) {
    const short* p = sup + (size_t)tid * 8192 + kbase + s * 32;
    ar[0] = *(const short8*)(p);      ar[1] = *(const short8*)(p + 8);
    ar[2] = *(const short8*)(p + 16); ar[3] = *(const short8*)(p + 24);
  };
  auto loadB = [&](int s) {
    const float* q = adjp + (size_t)s * 32;
    br[0] = *(const f32x4*)(q);
    br[1] = *(const f32x4*)(q + (1ull << 26));
    br[2] = *(const f32x4*)(q + (2ull << 26));
    br[3] = *(const f32x4*)(q + (3ull << 26));
  };
  loadA(0); loadB(0);
  for (int s = 0; s < nsteps; s++) {
    short* ad = As + tid * LP;
    *(short8*)(ad) = ar[0]; *(short8*)(ad + 8) = ar[1];
    *(short8*)(ad + 16) = ar[2]; *(short8*)(ad + 24) = ar[3];
    short4t bo;
    for (int j = 0; j < 4; j++)
      bo[j] = f2bf(t0 * br[0][j] + t1 * br[1][j] + t2 * br[2][j] + t3 * br[3][j]);
    *(short4t*)(Bs + bm * LP + bk) = bo;
    __syncthreads();
    if (s + 1 < nsteps) { loadA(s + 1); loadB(s + 1); }  // HBM latency hides under MFMA
    short8 af[8], bfr[2];
    for (int nf = 0; nf < 8; nf++)
      af[nf] = *(const short8*)(As + (wn * 128 + nf * 16 + lr) * LP + lk * 8);
    for (int mf = 0; mf < 2; mf++)
      bfr[mf] = *(const short8*)(Bs + (wm * 32 + mf * 16 + lr) * LP + lk * 8);
    for (int nf = 0; nf < 8; nf++)
      for (int mf = 0; mf < 2; mf++)
        acc[nf][mf] = __builtin_amdgcn_mfma_f32_16x16x32_bf16(af[nf], bfr[mf], acc[nf][mf], 0, 0, 0);
    __syncthreads();
  }
  for (int nf = 0; nf < 8; nf++) {
    int n = wn * 128 + nf * 16 + lk * 4;
    for (int mf = 0; mf < 2; mf++) {
      int m = m0 + wm * 32 + mf * 16 + lr;
      f32x4 v = acc[nf][mf];
      if (ksplit == 1) {
        for (int j = 0; j < 4; j++) v[j] = lrelu(v[j]);
        *(f32x4*)(outp + (size_t)m * 512 + n) = v;
      } else {
        *(f32x4*)(part + (size_t)kc * (8192 * 512) + (size_t)m * 512 + n) = v;
      }
    }
  }
}

// ---------------- Kernel 3: reduce K-split partials + LeakyReLU ----------------
__global__ __launch_bounds__(256) void k_reduce(const float* __restrict__ part,
                                                float* __restrict__ outp) {
  const size_t total = (size_t)8192 * 512 / 4;
  for (size_t i = (size_t)blockIdx.x * 256 + threadIdx.x; i < total;
       i += (size_t)gridDim.x * 256) {
    f32x4 a = *(const f32x4*)(part + i * 4);
    f32x4 b = *(const f32x4*)(part + (size_t)8192 * 512 + i * 4);
    f32x4 v;
    for (int j = 0; j < 4; j++) v[j] = lrelu(a[j] + b[j]);
    *(f32x4*)(outp + i * 4) = v;
  }
}

extern "C" void kernel_launch(void* const* d_in, const int* in_sizes, int n_in,
                              void* d_out, int out_size, void* d_ws, size_t ws_size,
                              hipStream_t stream) {
  const float* inputs = (const float*)d_in[0];
  const float* adj    = (const float*)d_in[1];
  const float* att    = (const float*)d_in[2];
  const float* w      = (const float*)d_in[3];
  const float* bias   = (const float*)d_in[4];
  float* outp = (float*)d_out;

  char* ws = (char*)d_ws;
  short* sup  = (short*)(ws);                 // 8 MB  supportT bf16 [512][8192]
  short* wt   = (short*)(ws + (8u << 20));    // 512 KB wT bf16 [512][512]
  float* part = (float*)(ws + (9u << 20));    // ksplit x 16 MB fp32 partials

  size_t need2 = (9ull << 20) + 2ull * 8192 * 512 * 4;
  int ksplit = (ws_size >= need2) ? 2 : 1;

  k_wt<<<64, 256, 0, stream>>>(w, wt);
  k_support<<<128, 512, 0, stream>>>(inputs, wt, bias, sup);
  dim3 g2(128, (unsigned)ksplit);
  k_main<<<g2, 512, 0, stream>>>(adj, att, sup, part, outp, ksplit);
  if (ksplit == 2) k_reduce<<<2048, 256, 0, stream>>>(part, outp);
}

// Round 2
// 337.297 us; speedup vs baseline: 1.0609x; 1.0609x over previous
//
#include <hip/hip_runtime.h>

#define LP 40  // padded LDS row length (bf16 elems) for Bs

typedef __attribute__((ext_vector_type(8))) short short8;
typedef __attribute__((ext_vector_type(4))) short short4t;
typedef __attribute__((ext_vector_type(4))) float f32x4;

__device__ __forceinline__ short f2bf(float f) {
  unsigned u = __builtin_bit_cast(unsigned, f);
  u += 0x7FFFu + ((u >> 16) & 1u);   // round-to-nearest-even
  return (short)(u >> 16);
}

__device__ __forceinline__ float lrelu(float v) { return v >= 0.f ? v : 0.2f * v; }

// ---------------- Kernel 0: wT bf16 [512][512]  (wt[n][c] = w[c][n]) ----------------
__global__ __launch_bounds__(256) void k_wt(const float* __restrict__ w,
                                            short* __restrict__ wt) {
  __shared__ float t[64][65];
  int c0 = (blockIdx.x & 7) * 64;
  int n0 = (blockIdx.x >> 3) * 64;
  int r  = threadIdx.x >> 4;
  int q4 = (threadIdx.x & 15) * 4;
  for (int i = 0; i < 4; i++) {
    int c = r + i * 16;
    f32x4 v = *(const f32x4*)(w + (size_t)(c0 + c) * 512 + (n0 + q4));
    t[c][q4 + 0] = v[0]; t[c][q4 + 1] = v[1]; t[c][q4 + 2] = v[2]; t[c][q4 + 3] = v[3];
  }
  __syncthreads();
  for (int i = 0; i < 4; i++) {
    int n = r + i * 16;
    short4t o;
    for (int j = 0; j < 4; j++) o[j] = f2bf(t[q4 + j][n]);
    *(short4t*)(wt + (size_t)(n0 + n) * 512 + (c0 + q4)) = o;
  }
}

// ------------- Kernel 1: supportT bf16 [512][8192] = (inputs @ w + b)^T -------------
__global__ __launch_bounds__(512, 2) void k_support(const float* __restrict__ inp,
                                                    const short* __restrict__ wt,
                                                    const float* __restrict__ bias,
                                                    short* __restrict__ sup) {
  __shared__ __align__(16) short As[512 * LP];
  __shared__ __align__(16) short Bs[64 * LP];
  const int tid = threadIdx.x;
  const int m0 = blockIdx.x * 64;
  const int wave = tid >> 6, lane = tid & 63;
  const int wn = wave >> 1, wm = wave & 1;
  const int lr = lane & 15, lk = lane >> 4;
  const int bm = tid >> 3, bk = (tid & 7) * 4;
  f32x4 acc[8][2] = {};
  short8 ar[4]; f32x4 br;
  auto loadA = [&](int s) {
    const short* p = wt + (size_t)tid * 512 + s * 32;
    ar[0] = *(const short8*)(p);      ar[1] = *(const short8*)(p + 8);
    ar[2] = *(const short8*)(p + 16); ar[3] = *(const short8*)(p + 24);
  };
  auto loadB = [&](int s) {
    br = *(const f32x4*)(inp + (size_t)(m0 + bm) * 512 + s * 32 + bk);
  };
  loadA(0); loadB(0);
  for (int s = 0; s < 16; s++) {
    short* ad = As + tid * LP;
    *(short8*)(ad) = ar[0]; *(short8*)(ad + 8) = ar[1];
    *(short8*)(ad + 16) = ar[2]; *(short8*)(ad + 24) = ar[3];
    short4t bo;
    for (int j = 0; j < 4; j++) bo[j] = f2bf(br[j]);
    *(short4t*)(Bs + bm * LP + bk) = bo;
    __syncthreads();
    if (s + 1 < 16) { loadA(s + 1); loadB(s + 1); }
    short8 af[8], bfr[2];
    for (int nf = 0; nf < 8; nf++)
      af[nf] = *(const short8*)(As + (wn * 128 + nf * 16 + lr) * LP + lk * 8);
    for (int mf = 0; mf < 2; mf++)
      bfr[mf] = *(const short8*)(Bs + (wm * 32 + mf * 16 + lr) * LP + lk * 8);
    for (int nf = 0; nf < 8; nf++)
      for (int mf = 0; mf < 2; mf++)
        acc[nf][mf] = __builtin_amdgcn_mfma_f32_16x16x32_bf16(af[nf], bfr[mf], acc[nf][mf], 0, 0, 0);
    __syncthreads();
  }
  for (int nf = 0; nf < 8; nf++) {
    int nb = wn * 128 + nf * 16 + lk * 4;
    for (int mf = 0; mf < 2; mf++) {
      int m = m0 + wm * 32 + mf * 16 + lr;
      for (int j = 0; j < 4; j++) {
        int n = nb + j;
        sup[(size_t)n * 8192 + m] = f2bf(acc[nf][mf][j] + bias[n]);
      }
    }
  }
}

// ---- Kernel 2: BM=128, BN=512. 8 waves, each owns 64n x 128m. A-frags direct
// ---- from L2-resident sup (no As LDS); adj reg-prefetch -> combine -> dbuf Bs.
__global__ __launch_bounds__(512, 2) void k_main(const float* __restrict__ adj,
                                                 const float* __restrict__ att,
                                                 const short* __restrict__ sup,
                                                 float* __restrict__ part,
                                                 float* __restrict__ outp,
                                                 int ksplit) {
  __shared__ __align__(16) short Bs[2][128 * LP];
  const int tid = threadIdx.x;
  const int b = blockIdx.x;
  // XCD swizzle: pin each kc to 8/ksplit XCDs so the 512 x kchunk sup slice
  // (2 MB at ksplit=4) stays resident in that XCD's 4 MB L2.
  const int xpk = 8 / ksplit;
  const int xcd = b & 7;
  const int kc = xcd / xpk;
  const int m0 = ((b >> 3) * xpk + (xcd % xpk)) * 128;
  const int kchunk = 8192 / ksplit;
  const int nsteps = kchunk / 32;
  const int kbase = kc * kchunk;
  const float t0 = att[0], t1 = att[1], t2 = att[2], t3 = att[3];
  const int wave = tid >> 6, lane = tid & 63;
  const int lr = lane & 15, lk = lane >> 4;
  const int srow = tid >> 2, koff = (tid & 3) * 8;   // staging map
  f32x4 acc[4][8] = {};                              // [nf][mf]
  const float* adjp = adj + (size_t)(m0 + srow) * 8192 + kbase + koff;
  const short* supp = sup + (size_t)(wave * 64 + lr) * 8192 + kbase + lk * 8;
  f32x4 br[8];
  auto loadAdj = [&](int s) {
    const float* q = adjp + (size_t)s * 32;
#pragma unroll
    for (int mt = 0; mt < 4; mt++) {
      br[mt * 2]     = __builtin_nontemporal_load((const f32x4*)(q + ((size_t)mt << 26)));
      br[mt * 2 + 1] = __builtin_nontemporal_load((const f32x4*)(q + ((size_t)mt << 26) + 4));
    }
  };
  loadAdj(0);
  int p = 0;
  for (int s = 0; s < nsteps; s++) {
    // issue A-frag loads early (L2-hit sup) — hidden under combine + barrier
    short8 af[4];
#pragma unroll
    for (int nf = 0; nf < 4; nf++)
      af[nf] = *(const short8*)(supp + (size_t)(nf * 16) * 8192 + s * 32);
    // combine 4 adj mats -> bf16 -> Bs[p]
    short8 bo;
#pragma unroll
    for (int k2 = 0; k2 < 8; k2++) {
      int h = k2 >> 2, j = k2 & 3;
      float c = t0 * br[h][j] + t1 * br[2 + h][j] + t2 * br[4 + h][j] + t3 * br[6 + h][j];
      bo[k2] = f2bf(c);
    }
    *(short8*)(Bs[p] + srow * LP + koff) = bo;
    __syncthreads();
    if (s + 1 < nsteps) loadAdj(s + 1);   // HBM prefetch spans MFMA phase
    short8 bfr[8];
#pragma unroll
    for (int mf = 0; mf < 8; mf++)
      bfr[mf] = *(const short8*)(Bs[p] + (mf * 16 + lr) * LP + lk * 8);
#pragma unroll
    for (int nf = 0; nf < 4; nf++)
#pragma unroll
      for (int mf = 0; mf < 8; mf++)
        acc[nf][mf] = __builtin_amdgcn_mfma_f32_16x16x32_bf16(af[nf], bfr[mf], acc[nf][mf], 0, 0, 0);
    p ^= 1;   // dbuf: next iter writes the other buffer — single barrier/step
  }
#pragma unroll
  for (int nf = 0; nf < 4; nf++) {
    int n = wave * 64 + nf * 16 + lk * 4;
#pragma unroll
    for (int mf = 0; mf < 8; mf++) {
      int m = m0 + mf * 16 + lr;
      f32x4 v = acc[nf][mf];
      if (ksplit == 1) {
        for (int j = 0; j < 4; j++) v[j] = lrelu(v[j]);
        __builtin_nontemporal_store(v, (f32x4*)(outp + (size_t)m * 512 + n));
      } else {
        __builtin_nontemporal_store(v, (f32x4*)(part + ((size_t)kc << 22) + (size_t)m * 512 + n));
      }
    }
  }
}

// ---------------- Kernel 3: reduce K-split partials + LeakyReLU ----------------
__global__ __launch_bounds__(256) void k_reduce(const float* __restrict__ part,
                                                float* __restrict__ outp, int ksplit) {
  const size_t total = (size_t)8192 * 512 / 4;
  for (size_t i = (size_t)blockIdx.x * 256 + threadIdx.x; i < total;
       i += (size_t)gridDim.x * 256) {
    f32x4 a = __builtin_nontemporal_load((const f32x4*)(part + i * 4));
    for (int k = 1; k < ksplit; k++) {
      f32x4 bv = __builtin_nontemporal_load((const f32x4*)(part + ((size_t)k << 22) + i * 4));
      for (int j = 0; j < 4; j++) a[j] += bv[j];
    }
    f32x4 v;
    for (int j = 0; j < 4; j++) v[j] = lrelu(a[j]);
    __builtin_nontemporal_store(v, (f32x4*)(outp + i * 4));
  }
}

extern "C" void kernel_launch(void* const* d_in, const int* in_sizes, int n_in,
                              void* d_out, int out_size, void* d_ws, size_t ws_size,
                              hipStream_t stream) {
  const float* inputs = (const float*)d_in[0];
  const float* adj    = (const float*)d_in[1];
  const float* att    = (const float*)d_in[2];
  const float* w      = (const float*)d_in[3];
  const float* bias   = (const float*)d_in[4];
  float* outp = (float*)d_out;

  char* ws = (char*)d_ws;
  short* sup  = (short*)(ws);                 // 8 MB  supportT bf16 [512][8192]
  short* wt   = (short*)(ws + (8u << 20));    // 512 KB wT bf16 [512][512]
  float* part = (float*)(ws + (9u << 20));    // ksplit x 16 MB fp32 partials

  const size_t base = (9ull << 20), psz = (1ull << 24);
  int ksplit = 1;
  if (ws_size >= base + 4 * psz) ksplit = 4;
  else if (ws_size >= base + 2 * psz) ksplit = 2;

  k_wt<<<64, 256, 0, stream>>>(w, wt);
  k_support<<<128, 512, 0, stream>>>(inputs, wt, bias, sup);
  k_main<<<64 * ksplit, 512, 0, stream>>>(adj, att, sup, part, outp, ksplit);
  if (ksplit > 1) k_reduce<<<1024, 256, 0, stream>>>(part, outp, ksplit);
}